// Round 3
// baseline (483.187 us; speedup 1.0000x reference)
//
#include <hip/hip_runtime.h>
#include <math.h>

#define NWAY 5
#define KSHOT 5
#define BB 4
#define QQ 75
#define CC 640
#define MM 196
#define BQ (BB*QQ)          // 300
#define MP 208              // packed A rows per bq
#define NCOL 1024           // padded flat col space (980 real)
#define NREAL 980

// ---- ws layout (float offsets) ----
#define BPK_OFF   0
#define BPK_SZF   (BB*NCOL*CC/2)            // 1,310,720 (fp16 region)
#define APK_OFF   (BPK_OFF + BPK_SZF)
#define APK_SZF   ((BQ*MP + 64)*CC/2)       // +64 pad rows so 256-row tile OOB stays in-region
#define GSTAT_OFF (APK_OFF + APK_SZF)       // even -> 8B aligned
#define GSTAT_N   (BQ*NWAY*MP)              // 312,000 u64
#define NRMS_OFF  (GSTAT_OFF + 2*GSTAT_N)
#define NRMS_SZ   (BB*NWAY*MM)              // 3,920
#define NRMQ_OFF  (NRMS_OFF + NRMS_SZ)
#define NRMQ_SZ   (BQ*MM)                   // 58,800

typedef __attribute__((ext_vector_type(8))) _Float16 half8;
typedef __attribute__((ext_vector_type(4))) float floatx4;

// ---------------- fused prep: A-pack (3000 blocks) + B mean-pack (200 blocks) ----------------
__global__ void k_prep(const float* __restrict__ sx, const float* __restrict__ qx,
                       _Float16* __restrict__ Apk, _Float16* __restrict__ Bpk,
                       float* __restrict__ nrmq, float* __restrict__ nrms) {
    __shared__ float T[64 * 197];         // 50,432 B
    int t = threadIdx.x;
    int blk = blockIdx.x;
    if (blk < 3000) {
        // ---- query pack: Apk[bq][m][c] fp16 (unnormalized) + nrmq partials ----
        int bq = blk / 10, cc = blk % 10;
        int c0 = cc * 64;
        const float* Q = qx + (size_t)bq * CC * MM + (size_t)c0 * MM;
        for (int idx = t; idx < 64 * MM; idx += 256) {
            int ci = idx / MM, m = idx - ci * MM;
            T[ci * 197 + m] = Q[idx];
        }
        __syncthreads();
        _Float16* out = Apk + (size_t)bq * MP * CC;
        int mloc = t >> 3, cj8 = t & 7;   // 32 rows x 8 col-groups per pass
        #pragma unroll
        for (int r = 0; r < 7; r++) {
            int mm = r * 32 + mloc;
            if (mm < MP) {
                half8 v;
                #pragma unroll
                for (int k = 0; k < 8; k++) {
                    float f = (mm < MM) ? T[(cj8 * 8 + k) * 197 + mm] : 0.f;
                    v[k] = (_Float16)f;
                }
                *(half8*)&out[(size_t)mm * CC + c0 + cj8 * 8] = v;
            }
        }
        if (t < MM) {
            float ss = 0.f;
            for (int ci = 0; ci < 64; ci++) { float v = T[ci * 197 + t]; ss += v * v; }
            atomicAdd(&nrmq[bq * MM + t], ss);
        }
    } else {
        // ---- support k-shot mean + pack: Bpk[b][col=n*196+ms][c] fp16 (unnormalized) + nrms ----
        int bb = blk - 3000;
        int bn = bb / 10, cc = bb % 10;
        int b = bn / NWAY, n = bn % NWAY;
        int c0 = cc * 64;
        const float* S = sx + (size_t)bn * KSHOT * CC * MM + (size_t)c0 * MM;
        for (int idx = t; idx < 64 * MM; idx += 256) {
            int ci = idx / MM, m = idx - ci * MM;
            float s = 0.f;
            #pragma unroll
            for (int k = 0; k < KSHOT; k++) s += S[(size_t)k * CC * MM + idx];
            T[ci * 197 + m] = s * 0.2f;
        }
        __syncthreads();
        _Float16* out = Bpk + ((size_t)b * NCOL + (size_t)n * MM) * CC;
        int mloc = t >> 3, cj8 = t & 7;
        #pragma unroll
        for (int r = 0; r < 7; r++) {
            int mm = r * 32 + mloc;
            if (mm < MM) {
                half8 v;
                #pragma unroll
                for (int k = 0; k < 8; k++)
                    v[k] = (_Float16)T[(cj8 * 8 + k) * 197 + mm];
                *(half8*)&out[(size_t)mm * CC + c0 + cj8 * 8] = v;
            }
        }
        if (t < MM) {
            float ss = 0.f;
            for (int ci = 0; ci < 64; ci++) { float v = T[ci * 197 + t]; ss += v * v; }
            atomicAdd(&nrms[bn * MM + t], ss);
        }
    }
}

// ---------------- MFMA similarity v3: 256x256, 8 waves, BK=64, 8-PHASE schedule ----------------
// m201-template port: each K-tile = 4 quadrant-phases of 16 MFMA; per phase:
//   {ds_read quadrant frags; [stage next tile @P0]; s_barrier; lgkmcnt(0)+sched_barrier;
//    setprio(1); MFMA; setprio(0); s_barrier}
// Single vmcnt(0) per K-tile at the P3 boundary — drains stage loads issued ~3 phases
// (~2000 cyc) earlier, so the wait is counted-equivalent (waits on nothing recent).
// Raw s_barrier (no implicit vmcnt/lgkm drain); rule #18: sched_barrier(0) after asm waits.
// wm=1 waves: rows 208..255 are pad -> mh=1 phases compute only mi=0 (4 MFMA).
__global__ __launch_bounds__(512, 2) void k_sim(
    const _Float16* __restrict__ Apk, const _Float16* __restrict__ Bpk,
    const float* __restrict__ nrms, unsigned long long* __restrict__ gstat)
{
    __shared__ __align__(16) _Float16 Lds[65536];   // 131,072 B

    int hw = blockIdx.x;
    int logical = (hw & 7) * 150 + (hw >> 3);   // XCD-bijective: 4 col-blocks of a bq per XCD
    int bq = logical >> 2, cblk = logical & 3;
    int b = bq / QQ;

    int t = threadIdx.x, w = t >> 6, lane = t & 63;
    int wm = w >> 2, wn = w & 3;
    int q = lane >> 4, l15 = lane & 15, s7 = l15 & 7;

    const _Float16* Ab = Apk + (size_t)bq * MP * CC;
    const _Float16* Bb = Bpk + ((size_t)b * NCOL + (size_t)cblk * 256) * CC;

    // staging source offsets (halfs): call a covers rows/cols a*64 .. +63, 8KB per call
    int voff[4];
    {
        int rr = t >> 3, slot = t & 7;
        #pragma unroll
        for (int a = 0; a < 4; a++) {
            int r = a * 64 + rr;
            voff[a] = r * CC + ((slot ^ (r & 7)) << 3);
        }
    }

    // fragment read bases (halfs, within one 32768-half buffer)
    int aoff[8], boff[4];
    #pragma unroll
    for (int m = 0; m < 8; m++) aoff[m] = (wm * 128 + m * 16 + l15) * 64;
    #pragma unroll
    for (int n = 0; n < 4; n++) boff[n] = 16384 + (wn * 64 + n * 16 + l15) * 64;

    floatx4 acc[8][4];
    #pragma unroll
    for (int m = 0; m < 8; m++)
        #pragma unroll
        for (int n = 0; n < 4; n++) acc[m][n] = (floatx4){0.f, 0.f, 0.f, 0.f};

    half8 af[4][2], bf[2][2];

    #define STAGE(TT)                                                                  \
        do {                                                                           \
            int nb_ = ((TT) & 1) << 15;                                                \
            int c0_ = (TT) * 64;                                                       \
            _Pragma("unroll")                                                          \
            for (int a = 0; a < 4; a++) {                                              \
                __builtin_amdgcn_global_load_lds(                                      \
                    (const __attribute__((address_space(1))) void*)(Ab + voff[a] + c0_),\
                    (__attribute__((address_space(3))) void*)(Lds + nb_ + a * 4096 + w * 512), \
                    16, 0, 0);                                                         \
                __builtin_amdgcn_global_load_lds(                                      \
                    (const __attribute__((address_space(1))) void*)(Bb + voff[a] + c0_),\
                    (__attribute__((address_space(3))) void*)(Lds + nb_ + 16384 + a * 4096 + w * 512), \
                    16, 0, 0);                                                         \
            }                                                                          \
        } while (0)

    #define BARR() __builtin_amdgcn_s_barrier()
    #define WAIT_LGKM0() do { asm volatile("s_waitcnt lgkmcnt(0)" ::: "memory"); \
                              __builtin_amdgcn_sched_barrier(0); } while (0)
    #define WAIT_VM0()   do { asm volatile("s_waitcnt vmcnt(0)" ::: "memory");   \
                              __builtin_amdgcn_sched_barrier(0); } while (0)

    #define READ_AF(MH)                                                                \
        _Pragma("unroll")                                                              \
        for (int mi = 0; mi < 4; mi++)                                                 \
            _Pragma("unroll")                                                          \
            for (int ks = 0; ks < 2; ks++)                                             \
                af[mi][ks] = *(const half8*)&Lds[cb + aoff[(MH)*4+mi] + (((ks*4+q)^s7)<<3)];
    #define READ_AF1_TRIM()                                                            \
        _Pragma("unroll")                                                              \
        for (int ks = 0; ks < 2; ks++)                                                 \
            af[0][ks] = *(const half8*)&Lds[cb + aoff[4] + (((ks*4+q)^s7)<<3)];
    #define READ_BF(NH)                                                                \
        _Pragma("unroll")                                                              \
        for (int ni = 0; ni < 2; ni++)                                                 \
            _Pragma("unroll")                                                          \
            for (int ks = 0; ks < 2; ks++)                                             \
                bf[ni][ks] = *(const half8*)&Lds[cb + boff[(NH)*2+ni] + (((ks*4+q)^s7)<<3)];
    #define MFMA_Q(MH,NH)                                                              \
        _Pragma("unroll")                                                              \
        for (int mi = 0; mi < 4; mi++)                                                 \
            _Pragma("unroll")                                                          \
            for (int ni = 0; ni < 2; ni++)                                             \
                _Pragma("unroll")                                                      \
                for (int ks = 0; ks < 2; ks++)                                         \
                    acc[(MH)*4+mi][(NH)*2+ni] = __builtin_amdgcn_mfma_f32_16x16x32_f16( \
                        af[mi][ks], bf[ni][ks], acc[(MH)*4+mi][(NH)*2+ni], 0, 0, 0);
    #define MFMA_Q1_TRIM(NH)                                                           \
        _Pragma("unroll")                                                              \
        for (int ni = 0; ni < 2; ni++)                                                 \
            _Pragma("unroll")                                                          \
            for (int ks = 0; ks < 2; ks++)                                             \
                acc[4][(NH)*2+ni] = __builtin_amdgcn_mfma_f32_16x16x32_f16(            \
                    af[0][ks], bf[ni][ks], acc[4][(NH)*2+ni], 0, 0, 0);

    // prologue: tile 0 -> buf 0
    STAGE(0);
    WAIT_VM0();
    BARR();

    for (int tt = 0; tt < 10; tt++) {
        int cb = (tt & 1) << 15;

        // ---- P0: quadrant (mh0, nh0); stage next tile ----
        READ_AF(0); READ_BF(0);
        if (tt < 9) STAGE(tt + 1);
        BARR();
        WAIT_LGKM0();
        __builtin_amdgcn_s_setprio(1);
        MFMA_Q(0, 0);
        __builtin_amdgcn_s_setprio(0);
        BARR();

        // ---- P1: quadrant (mh1, nh0) ----
        if (wm == 0) { READ_AF(1); } else { READ_AF1_TRIM(); }
        BARR();
        WAIT_LGKM0();
        __builtin_amdgcn_s_setprio(1);
        if (wm == 0) { MFMA_Q(1, 0); } else { MFMA_Q1_TRIM(0); }
        __builtin_amdgcn_s_setprio(0);
        BARR();

        // ---- P2: quadrant (mh1, nh1) ----
        READ_BF(1);
        BARR();
        WAIT_LGKM0();
        __builtin_amdgcn_s_setprio(1);
        if (wm == 0) { MFMA_Q(1, 1); } else { MFMA_Q1_TRIM(1); }
        __builtin_amdgcn_s_setprio(0);
        BARR();

        // ---- P3: quadrant (mh0, nh1); tile boundary: drain next-tile stages ----
        READ_AF(0);
        BARR();
        WAIT_LGKM0();
        __builtin_amdgcn_s_setprio(1);
        MFMA_Q(0, 1);
        __builtin_amdgcn_s_setprio(0);
        WAIT_VM0();
        BARR();
    }

    // ---- epilogue: fold 4 nrep cols into <=2 class keys, 16-lane butterfly, atomicMax ----
    int wbase = cblk * 256 + wn * 64;     // 64-col window, straddles <=1 class boundary
    int clsLo = wbase / 196;
    int clsHi = clsLo + 1;
    bool hasHi = (((wbase + 63) / 196) != clsLo) && (clsHi < NWAY);
    float invv[4]; int msv[4], isLo[4], valid[4];
    #pragma unroll
    for (int n = 0; n < 4; n++) {
        int c = wbase + n * 16 + l15;
        int cls = c / 196;
        msv[n] = c - cls * 196;
        isLo[n] = (cls == clsLo);
        valid[n] = (c < NREAL);
        invv[n] = valid[n] ? (1.0f / fmaxf(sqrtf(nrms[b * NREAL + c]), 1e-8f)) : 0.f;
    }
    #pragma unroll
    for (int m = 0; m < 8; m++) {                 // static bound: acc stays in VGPRs
        if (wm == 1 && m >= 5) continue;          // uniform guard; rows >=208 are pad
        #pragma unroll
        for (int r = 0; r < 4; r++) {
            unsigned long long keyLo = 0ULL, keyHi = 0ULL;
            #pragma unroll
            for (int n = 0; n < 4; n++) {
                float v = acc[m][n][r] * invv[n];
                unsigned int ub = __float_as_uint(v);
                unsigned int su = (ub & 0x80000000u) ? ~ub : (ub | 0x80000000u);
                unsigned long long key = valid[n]
                    ? (((unsigned long long)su << 32) |
                       (unsigned long long)(0xFFFFFFFFu - (unsigned int)msv[n]))
                    : 0ULL;
                if (isLo[n]) keyLo = (key > keyLo) ? key : keyLo;
                else         keyHi = (key > keyHi) ? key : keyHi;
            }
            #pragma unroll
            for (int sft = 1; sft < 16; sft <<= 1) {
                unsigned long long o = __shfl_xor(keyLo, sft, 64);
                if (o > keyLo) keyLo = o;
            }
            if (hasHi) {
                #pragma unroll
                for (int sft = 1; sft < 16; sft <<= 1) {
                    unsigned long long o = __shfl_xor(keyHi, sft, 64);
                    if (o > keyHi) keyHi = o;
                }
            }
            if (l15 == 0) {
                int gm = wm * 128 + m * 16 + q * 4 + r;
                if (gm < MM) {
                    if (keyLo)
                        atomicMax(&gstat[((size_t)bq * NWAY + clsLo) * MP + gm], keyLo);
                    if (hasHi && keyHi)
                        atomicMax(&gstat[((size_t)bq * NWAY + clsHi) * MP + gm], keyHi);
                }
            }
        }
    }
}

// ---------------- mutual-NN mask + predict + per-sample CE -> atomicAdd out ----------------
__global__ void k_post(const unsigned long long* __restrict__ gstat,
                       const float* __restrict__ nrmq,
                       float* __restrict__ out, const int* __restrict__ qy) {
    int bq = blockIdx.x;
    int t = threadIdx.x;
    __shared__ float invq_s[MM];
    __shared__ float cm[NWAY * MM];
    __shared__ int   ca[NWAY * MM];
    __shared__ float gmax[MM];
    __shared__ int   jst[MM];
    __shared__ int   msk[MM];
    __shared__ float pred[NWAY];

    if (t < MM) invq_s[t] = 1.0f / fmaxf(sqrtf(nrmq[bq * MM + t]), 1e-8f);
    __syncthreads();

    for (int i = t; i < NWAY * MM; i += 256) {
        int n = i / MM, m = i - n * MM;
        unsigned long long key = gstat[((size_t)bq * NWAY + n) * MP + m];
        unsigned int hi = (unsigned int)(key >> 32);
        unsigned int bits = (hi & 0x80000000u) ? (hi ^ 0x80000000u) : ~hi;
        cm[i] = __uint_as_float(bits) * invq_s[m];
        ca[i] = (int)(0xFFFFFFFFu - (unsigned int)(key & 0xFFFFFFFFu));
    }
    __syncthreads();

    if (t < MM) {       // cross-class combine: ascending n, strict > == n-major first-index
        float bv = cm[t];
        int bj = ca[t];
        for (int n = 1; n < NWAY; n++) {
            float v = cm[n * MM + t];
            if (v > bv) { bv = v; bj = n * MM + ca[n * MM + t]; }
        }
        gmax[t] = bv; jst[t] = bj;
    }
    __syncthreads();

    if (t < MM) {       // mutual-NN: winner of my support-column group (max gmax, min index)
        int myj = jst[t];
        float myv = gmax[t];
        int lose = 0;
        for (int m2 = 0; m2 < MM; m2++) {
            if (jst[m2] == myj &&
                (gmax[m2] > myv || (gmax[m2] == myv && m2 < t))) lose = 1;
        }
        msk[t] = !lose;
    }
    __syncthreads();

    if (t < NWAY) {
        float p = 0.f;
        for (int m = 0; m < MM; m++) if (msk[m]) p += cm[t * MM + m];
        pred[t] = 2.0f * p;   // TEMPERATURE = 2
    }
    __syncthreads();

    if (t == 0) {
        float pm = pred[0];
        for (int n = 1; n < NWAY; n++) pm = fmaxf(pm, pred[n]);
        float s = 0.f;
        for (int n = 0; n < NWAY; n++) s += expf(pred[n] - pm);
        float lse = pm + logf(s);
        int y = qy[bq];
        atomicAdd(out, (lse - pred[y]) * (1.0f / (BB * QQ)));
    }
}

extern "C" void kernel_launch(void* const* d_in, const int* in_sizes, int n_in,
                              void* d_out, int out_size, void* d_ws, size_t ws_size,
                              hipStream_t stream) {
    const float* sx = (const float*)d_in[0];
    const float* qx = (const float*)d_in[2];
    const int*   qy = (const int*)d_in[3];
    float* out = (float*)d_out;
    float* ws  = (float*)d_ws;

    _Float16* Bpk = (_Float16*)(ws + BPK_OFF);
    _Float16* Apk = (_Float16*)(ws + APK_OFF);
    unsigned long long* gstat = (unsigned long long*)(ws + GSTAT_OFF);
    float* nrms = ws + NRMS_OFF;
    float* nrmq = ws + NRMQ_OFF;

    // zero gstat + nrms + nrmq (contiguous) and the output accumulator
    hipMemsetAsync(gstat, 0, (size_t)(2 * GSTAT_N + NRMS_SZ + NRMQ_SZ) * 4, stream);
    hipMemsetAsync(out, 0, 4, stream);
    hipLaunchKernelGGL(k_prep, dim3(3200), dim3(256), 0, stream, sx, qx, Apk, Bpk, nrmq, nrms);
    hipLaunchKernelGGL(k_sim,  dim3(1200), dim3(512), 0, stream, Apk, Bpk, nrms, gstat);
    hipLaunchKernelGGL(k_post, dim3(300), dim3(256), 0, stream, gstat, nrmq, out, qy);
}

// Round 4
// 446.797 us; speedup vs baseline: 1.0814x; 1.0814x over previous
//
#include <hip/hip_runtime.h>
#include <math.h>

#define NWAY 5
#define KSHOT 5
#define BB 4
#define QQ 75
#define CC 640
#define MM 196
#define BQ (BB*QQ)          // 300
#define MP 208              // packed A rows per bq
#define NCOL 1024           // padded flat col space (980 real)
#define NREAL 980

// ---- ws layout (float offsets) ----
#define BPK_OFF   0
#define BPK_SZF   (BB*NCOL*CC/2)            // 1,310,720 (fp16 region)
#define APK_OFF   (BPK_OFF + BPK_SZF)
#define APK_SZF   ((BQ*MP + 64)*CC/2)       // +64 pad rows so mblk=1 OOB stays in-region
#define GSTAT_OFF (APK_OFF + APK_SZF)       // even -> 8B aligned
#define GSTAT_N   (BQ*NWAY*MP)              // 312,000 u64
#define NRMS_OFF  (GSTAT_OFF + 2*GSTAT_N)
#define NRMS_SZ   (BB*NWAY*MM)              // 3,920
#define NRMQ_OFF  (NRMS_OFF + NRMS_SZ)
#define NRMQ_SZ   (BQ*MM)                   // 58,800

typedef __attribute__((ext_vector_type(8))) _Float16 half8;
typedef __attribute__((ext_vector_type(4))) float floatx4;

// ---------------- fused prep: A-pack (6000 blocks) + B mean-pack (400 blocks) ----------------
// 32-channel chunks (was 64): LDS 25,216 B -> 6 blocks/CU (was 3) for 2x latency hiding.
// Access patterns identical to the verified 64-ch version; pack reads now conflict-free
// (lane cj8-stride 8*197 words = 8 banks apart, only 4 lanes per group).
__global__ void k_prep(const float* __restrict__ sx, const float* __restrict__ qx,
                       _Float16* __restrict__ Apk, _Float16* __restrict__ Bpk,
                       float* __restrict__ nrmq, float* __restrict__ nrms) {
    __shared__ float T[32 * 197];         // 25,216 B
    int t = threadIdx.x;
    int blk = blockIdx.x;
    if (blk < 6000) {
        // ---- query pack: Apk[bq][m][c] fp16 (unnormalized) + nrmq partials ----
        int bq = blk / 20, cc = blk % 20;
        int c0 = cc * 32;
        const float* Q = qx + (size_t)bq * CC * MM + (size_t)c0 * MM;
        for (int idx = t; idx < 32 * MM; idx += 256) {
            int ci = idx / MM, m = idx - ci * MM;
            T[ci * 197 + m] = Q[idx];
        }
        __syncthreads();
        _Float16* out = Apk + (size_t)bq * MP * CC;
        int mloc = t >> 2, cj8 = t & 3;   // 64 rows x 4 col-groups per pass
        #pragma unroll
        for (int r = 0; r < 4; r++) {
            int mm = r * 64 + mloc;
            if (mm < MP) {
                half8 v;
                #pragma unroll
                for (int k = 0; k < 8; k++) {
                    float f = (mm < MM) ? T[(cj8 * 8 + k) * 197 + mm] : 0.f;
                    v[k] = (_Float16)f;
                }
                *(half8*)&out[(size_t)mm * CC + c0 + cj8 * 8] = v;
            }
        }
        if (t < MM) {
            float ss = 0.f;
            for (int ci = 0; ci < 32; ci++) { float v = T[ci * 197 + t]; ss += v * v; }
            atomicAdd(&nrmq[bq * MM + t], ss);
        }
    } else {
        // ---- support k-shot mean + pack: Bpk[b][col=n*196+ms][c] fp16 (unnormalized) + nrms ----
        int bb = blk - 6000;
        int bn = bb / 20, cc = bb % 20;
        int b = bn / NWAY, n = bn % NWAY;
        int c0 = cc * 32;
        const float* S = sx + (size_t)bn * KSHOT * CC * MM + (size_t)c0 * MM;
        for (int idx = t; idx < 32 * MM; idx += 256) {
            int ci = idx / MM, m = idx - ci * MM;
            float s = 0.f;
            #pragma unroll
            for (int k = 0; k < KSHOT; k++) s += S[(size_t)k * CC * MM + idx];
            T[ci * 197 + m] = s * 0.2f;
        }
        __syncthreads();
        _Float16* out = Bpk + ((size_t)b * NCOL + (size_t)n * MM) * CC;
        int mloc = t >> 2, cj8 = t & 3;
        #pragma unroll
        for (int r = 0; r < 4; r++) {
            int mm = r * 64 + mloc;
            if (mm < MM) {
                half8 v;
                #pragma unroll
                for (int k = 0; k < 8; k++)
                    v[k] = (_Float16)T[(cj8 * 8 + k) * 197 + mm];
                *(half8*)&out[(size_t)mm * CC + c0 + cj8 * 8] = v;
            }
        }
        if (t < MM) {
            float ss = 0.f;
            for (int ci = 0; ci < 32; ci++) { float v = T[ci * 197 + t]; ss += v * v; }
            atomicAdd(&nrms[bn * MM + t], ss);
        }
    }
}

// ---------------- MFMA similarity: 128x128 block, 2x8 wave tiling, segmented epilogue ----------------
// (verified round-0 structure, 161 us) + trim: in mblk=1 blocks wave 3's rows (224-255)
// are 100% pad -> skip its fragment reads + MFMA + epilogue (wave-uniform branch;
// staging + barriers untouched). Removes 12.5% of MFMA + LDS-fragment work.
// LDS: A 128 rows x 64 halfs (chunks 0-1023), B 128 cols x 64 halfs (chunks 1024-2047).
// Chunk slot j of row m holds global chunk j^(m&7) -> ds_read_b128 2-way aliased (free).
__global__ __launch_bounds__(256, 3) void k_sim(
    const _Float16* __restrict__ Apk, const _Float16* __restrict__ Bpk,
    const float* __restrict__ nrms, unsigned long long* __restrict__ gstat)
{
    __shared__ __align__(16) _Float16 Lds[16384];   // 32,768 B
    int id = blockIdx.x;
    int x = id & 7, s = id >> 3;          // XCD swizzle: 16 blocks of one bq -> same XCD
    int sub = s & 15, bqg = s >> 4;
    int bq = x + (bqg << 3);
    if (bq >= BQ) return;
    int mblk = sub >> 3, cblk = sub & 7;
    int b = bq / QQ;

    int t = threadIdx.x, lane = t & 63, w = t >> 6;
    int q = lane >> 4, l15 = lane & 15;
    bool active = !(mblk == 1 && w == 3);   // wave-uniform; rows 224-255 are pad garbage

    const _Float16* Ab = Apk + (size_t)bq * MP * CC + (size_t)(mblk * 128) * CC;
    const _Float16* Bb = Bpk + ((size_t)b * NCOL + (size_t)(cblk * 128)) * CC;
    const _Float16* base = (w < 2) ? Ab : Bb;     // waves 0,1 stage A; 2,3 stage B

    // per-lane 32-bit staging offsets (halfs)
    int voff[8];
    #pragma unroll
    for (int p = 0; p < 8; p++) {
        int chunk = (w * 8 + p) * 64 + lane;
        if (chunk < 1024) {
            int m = chunk >> 3, j = chunk & 7;
            voff[p] = m * CC + ((j ^ (m & 7)) << 3);
        } else {
            int cb = chunk - 1024;
            int jl = cb >> 3, j = cb & 7;
            voff[p] = jl * CC + ((j ^ (jl & 7)) << 3);
        }
    }

    // fragment LDS offsets (halfs): wave w -> rows w*32 + i*16, all 128 cols
    int arow[2], asw[2], brow[8], bsw[8];
    #pragma unroll
    for (int i = 0; i < 2; i++) {
        int m = w * 32 + i * 16 + l15;
        arow[i] = m * 64; asw[i] = m & 7;
    }
    #pragma unroll
    for (int jt = 0; jt < 8; jt++) {
        int jl = jt * 16 + l15;
        brow[jt] = 8192 + jl * 64; bsw[jt] = jl & 7;
    }

    floatx4 acc[2][8];
    #pragma unroll
    for (int i = 0; i < 2; i++)
        #pragma unroll
        for (int j = 0; j < 8; j++) acc[i][j] = (floatx4){0.f, 0.f, 0.f, 0.f};

    for (int c0 = 0; c0 < CC; c0 += 64) {
        #pragma unroll
        for (int p = 0; p < 8; p++)
            __builtin_amdgcn_global_load_lds(
                (const __attribute__((address_space(1))) void*)(base + voff[p] + c0),
                (__attribute__((address_space(3))) void*)(Lds + (w * 8 + p) * 512),
                16, 0, 0);
        __syncthreads();
        if (active) {
            #pragma unroll
            for (int ks = 0; ks < 2; ks++) {
                int cj = ks * 4 + q;
                half8 af[2], bf[8];
                #pragma unroll
                for (int i = 0; i < 2; i++)
                    af[i] = *(const half8*)&Lds[arow[i] + ((cj ^ asw[i]) << 3)];
                #pragma unroll
                for (int jt = 0; jt < 8; jt++)
                    bf[jt] = *(const half8*)&Lds[brow[jt] + ((cj ^ bsw[jt]) << 3)];
                #pragma unroll
                for (int i = 0; i < 2; i++)
                    #pragma unroll
                    for (int jt = 0; jt < 8; jt++)
                        acc[i][jt] = __builtin_amdgcn_mfma_f32_16x16x32_f16(af[i], bf[jt], acc[i][jt], 0, 0, 0);
            }
        }
        __syncthreads();
    }

    if (!active) return;   // after last barrier; epilogue is wave-local (shfl within wave)

    // epilogue: column norm applied here (B packed unnormalized); fold 8 jt into <=2
    // class keys per (i,r), dual-key butterfly, atomicMax
    int wbase = cblk * 128;               // all 4 waves share the col window
    int clsLo = wbase / 196;
    float invv[8]; int ms8[8], isLo[8], valid[8];
    #pragma unroll
    for (int jt = 0; jt < 8; jt++) {
        int c = wbase + jt * 16 + l15;
        int cls = c / 196;
        ms8[jt] = c - cls * 196;
        isLo[jt] = (cls == clsLo);
        valid[jt] = (c < NREAL);
        invv[jt] = valid[jt] ? (1.0f / fmaxf(sqrtf(nrms[b * NREAL + c]), 1e-8f)) : 0.f;
    }
    #pragma unroll
    for (int i = 0; i < 2; i++) {
        #pragma unroll
        for (int r = 0; r < 4; r++) {
            unsigned long long keyLo = 0ULL, keyHi = 0ULL;
            #pragma unroll
            for (int jt = 0; jt < 8; jt++) {
                float v = acc[i][jt][r] * invv[jt];
                unsigned int ub = __float_as_uint(v);
                unsigned int su = (ub & 0x80000000u) ? ~ub : (ub | 0x80000000u);
                unsigned long long key = valid[jt]
                    ? (((unsigned long long)su << 32) |
                       (unsigned long long)(0xFFFFFFFFu - (unsigned int)ms8[jt]))
                    : 0ULL;
                if (isLo[jt]) keyLo = (key > keyLo) ? key : keyLo;
                else          keyHi = (key > keyHi) ? key : keyHi;
            }
            #pragma unroll
            for (int sft = 1; sft < 16; sft <<= 1) {
                unsigned long long oL = __shfl_xor(keyLo, sft, 64);
                unsigned long long oH = __shfl_xor(keyHi, sft, 64);
                if (oL > keyLo) keyLo = oL;
                if (oH > keyHi) keyHi = oH;
            }
            if (l15 == 0) {
                int gm = mblk * 128 + w * 32 + i * 16 + q * 4 + r;
                if (gm < MM) {
                    if (keyLo)
                        atomicMax(&gstat[((size_t)bq * NWAY + clsLo) * MP + gm], keyLo);
                    int clsHi = clsLo + 1;
                    if (keyHi && clsHi < NWAY)
                        atomicMax(&gstat[((size_t)bq * NWAY + clsHi) * MP + gm], keyHi);
                }
            }
        }
    }
}

// ---------------- mutual-NN mask + predict + per-sample CE -> atomicAdd out ----------------
__global__ void k_post(const unsigned long long* __restrict__ gstat,
                       const float* __restrict__ nrmq,
                       float* __restrict__ out, const int* __restrict__ qy) {
    int bq = blockIdx.x;
    int t = threadIdx.x;
    __shared__ float invq_s[MM];
    __shared__ float cm[NWAY * MM];
    __shared__ int   ca[NWAY * MM];
    __shared__ float gmax[MM];
    __shared__ int   jst[MM];
    __shared__ int   msk[MM];
    __shared__ float pred[NWAY];

    if (t < MM) invq_s[t] = 1.0f / fmaxf(sqrtf(nrmq[bq * MM + t]), 1e-8f);
    __syncthreads();

    for (int i = t; i < NWAY * MM; i += 256) {
        int n = i / MM, m = i - n * MM;
        unsigned long long key = gstat[((size_t)bq * NWAY + n) * MP + m];
        unsigned int hi = (unsigned int)(key >> 32);
        unsigned int bits = (hi & 0x80000000u) ? (hi ^ 0x80000000u) : ~hi;
        cm[i] = __uint_as_float(bits) * invq_s[m];
        ca[i] = (int)(0xFFFFFFFFu - (unsigned int)(key & 0xFFFFFFFFu));
    }
    __syncthreads();

    if (t < MM) {       // cross-class combine: ascending n, strict > == n-major first-index
        float bv = cm[t];
        int bj = ca[t];
        for (int n = 1; n < NWAY; n++) {
            float v = cm[n * MM + t];
            if (v > bv) { bv = v; bj = n * MM + ca[n * MM + t]; }
        }
        gmax[t] = bv; jst[t] = bj;
    }
    __syncthreads();

    if (t < MM) {       // mutual-NN: winner of my support-column group (max gmax, min index)
        int myj = jst[t];
        float myv = gmax[t];
        int lose = 0;
        for (int m2 = 0; m2 < MM; m2++) {
            if (jst[m2] == myj &&
                (gmax[m2] > myv || (gmax[m2] == myv && m2 < t))) lose = 1;
        }
        msk[t] = !lose;
    }
    __syncthreads();

    if (t < NWAY) {
        float p = 0.f;
        for (int m = 0; m < MM; m++) if (msk[m]) p += cm[t * MM + m];
        pred[t] = 2.0f * p;   // TEMPERATURE = 2
    }
    __syncthreads();

    if (t == 0) {
        float pm = pred[0];
        for (int n = 1; n < NWAY; n++) pm = fmaxf(pm, pred[n]);
        float s = 0.f;
        for (int n = 0; n < NWAY; n++) s += expf(pred[n] - pm);
        float lse = pm + logf(s);
        int y = qy[bq];
        atomicAdd(out, (lse - pred[y]) * (1.0f / (BB * QQ)));
    }
}

extern "C" void kernel_launch(void* const* d_in, const int* in_sizes, int n_in,
                              void* d_out, int out_size, void* d_ws, size_t ws_size,
                              hipStream_t stream) {
    const float* sx = (const float*)d_in[0];
    const float* qx = (const float*)d_in[2];
    const int*   qy = (const int*)d_in[3];
    float* out = (float*)d_out;
    float* ws  = (float*)d_ws;

    _Float16* Bpk = (_Float16*)(ws + BPK_OFF);
    _Float16* Apk = (_Float16*)(ws + APK_OFF);
    unsigned long long* gstat = (unsigned long long*)(ws + GSTAT_OFF);
    float* nrms = ws + NRMS_OFF;
    float* nrmq = ws + NRMQ_OFF;

    // zero gstat + nrms + nrmq (contiguous) and the output accumulator
    hipMemsetAsync(gstat, 0, (size_t)(2 * GSTAT_N + NRMS_SZ + NRMQ_SZ) * 4, stream);
    hipMemsetAsync(out, 0, 4, stream);
    hipLaunchKernelGGL(k_prep, dim3(6400), dim3(256), 0, stream, sx, qx, Apk, Bpk, nrmq, nrms);
    hipLaunchKernelGGL(k_sim,  dim3(8 * 38 * 16), dim3(256), 0, stream, Apk, Bpk, nrms, gstat);
    hipLaunchKernelGGL(k_post, dim3(300), dim3(256), 0, stream, gstat, nrmq, out, qy);
}